// Round 1
// baseline (116.214 us; speedup 1.0000x reference)
//
#include <hip/hip_runtime.h>

#define B_ROWS 131072
#define NA 16
#define DD 513
#define ALPHA 0.1f
#define EPSV 1e-7f

__global__ __launch_bounds__(256, 2)
void hfield_kernel(const float* __restrict__ x,
                   const float* __restrict__ anc,
                   float* __restrict__ out) {
    __shared__ float lds_af[NA * DD];                       // raw anchors copy (col 0 unused)
    __shared__ __attribute__((aligned(16))) float redbuf[4][64 * 20];

    const int tid  = threadIdx.x;
    const int lane = tid & 63;
    const int wid  = tid >> 6;
    const int gw   = blockIdx.x * 4 + wid;                  // global wave id
    const int TW   = gridDim.x * 4;                         // total waves

    // stage anchors to LDS (for the y-gather)
    for (int i = tid; i < NA * DD; i += 256) lds_af[i] = anc[i];

    // per-lane anchor slice in registers: Areg[a][j] = af[a][1 + lane + 64j]
    float Areg[NA][8];
#pragma unroll
    for (int a = 0; a < NA; ++a) {
#pragma unroll
        for (int j = 0; j < 8; ++j)
            Areg[a][j] = anc[a * DD + 1 + lane + 64 * j];
    }

    float* wb = redbuf[wid];
    const int g     = lane >> 4;
    const int amine = lane & 15;

    // ---- af0 for my anchor: sqrt(1 + sum(sp^2)) (recomputed like reference _proj) ----
    float af0;
    {
        float q[NA];
#pragma unroll
        for (int a = 0; a < NA; ++a) {
            float s = 0.f;
#pragma unroll
            for (int j = 0; j < 8; ++j) s = fmaf(Areg[a][j], Areg[a][j], s);
            q[a] = s;
        }
#pragma unroll
        for (int t4 = 0; t4 < 4; ++t4)
            *reinterpret_cast<float4*>(&wb[lane * 20 + 4 * t4]) =
                make_float4(q[4 * t4], q[4 * t4 + 1], q[4 * t4 + 2], q[4 * t4 + 3]);
        asm volatile("s_waitcnt lgkmcnt(0)" ::: "memory");
        float t = 0.f;
#pragma unroll
        for (int k = 0; k < 16; ++k) t += wb[(g + 4 * k) * 20 + amine];
        t += __shfl_xor(t, 16);
        t += __shfl_xor(t, 32);
        af0 = sqrtf(1.0f + t);
    }

    __syncthreads();   // lds_af ready for all waves

    const float thmin = 1.0f + 1e-7f;

    int row = gw;
    float xn[8], x0n = 0.f;
    if (row < B_ROWS) {
        const float* rp = x + (size_t)row * DD;
        x0n = rp[0];
#pragma unroll
        for (int j = 0; j < 8; ++j) xn[j] = rp[1 + lane + 64 * j];
    }

    for (; row < B_ROWS; row += TW) {
        float xc[8];
        const float x0 = x0n;
#pragma unroll
        for (int j = 0; j < 8; ++j) xc[j] = xn[j];

        // prefetch next row
        const int nrow = row + TW;
        if (nrow < B_ROWS) {
            const float* rp = x + (size_t)nrow * DD;
            x0n = rp[0];
#pragma unroll
            for (int j = 0; j < 8; ++j) xn[j] = rp[1 + lane + 64 * j];
        }

        // per-lane partial dots (spatial part, all-positive; sign folded later)
        float q[NA];
#pragma unroll
        for (int a = 0; a < NA; ++a) {
            float s = 0.f;
#pragma unroll
            for (int j = 0; j < 8; ++j) s = fmaf(xc[j], Areg[a][j], s);
            q[a] = s;
        }

        // wave-private LDS transpose-reduce: 64 lanes x 16 -> per-lane total for anchor amine
#pragma unroll
        for (int t4 = 0; t4 < 4; ++t4)
            *reinterpret_cast<float4*>(&wb[lane * 20 + 4 * t4]) =
                make_float4(q[4 * t4], q[4 * t4 + 1], q[4 * t4 + 2], q[4 * t4 + 3]);
        asm volatile("s_waitcnt lgkmcnt(0)" ::: "memory");
        float t = 0.f;
#pragma unroll
        for (int k = 0; k < 16; ++k) t += wb[(g + 4 * k) * 20 + amine];
        t += __shfl_xor(t, 16);
        t += __shfl_xor(t, 32);

        // theta_a = x0*af0_a - sum_spatial ; clip
        float tc = fmaxf(fmaf(x0, af0, -t), thmin);
        int   bi = amine;

        // argmin over 16 anchors with first-index tie-break
#pragma unroll
        for (int m = 1; m <= 8; m <<= 1) {
            float vo = __shfl_xor(tc, m);
            int   io = __shfl_xor(bi, m);
            bool take = (vo < tc) || (vo == tc && io < bi);
            tc = take ? vo : tc;
            bi = take ? io : bi;
        }

        // scalar epilogue (wave-uniform, computed by all lanes)
        float s2   = tc * tc - 1.0f;
        float rr   = sqrtf(s2);
        float ach  = logf(tc + rr);              // arccosh
        float coef = ach / rr;
        float vn   = sqrtf(fmaxf(ALPHA * ALPHA * ach * ach, EPSV));
        float e    = expf(vn);
        float ei   = 1.0f / e;
        float ch   = 0.5f * (e + ei);
        float sh   = 0.5f * (e - ei);
        float c2   = ALPHA * coef * (sh / vn);
        float c1   = fmaf(-c2, tc, ch);

        // gather y from LDS and write out
        float* op = out + (size_t)row * DD;
        const float* yp = lds_af + bi * DD + 1 + lane;
#pragma unroll
        for (int j = 0; j < 8; ++j) {
            float y = yp[64 * j];
            __builtin_nontemporal_store(fmaf(c2, y, c1 * xc[j]), &op[1 + lane + 64 * j]);
        }
        float y0   = __shfl(af0, bi);            // af0 of winning anchor (lane bi holds it)
        float out0 = fmaf(c2, y0, c1 * x0);
        if (lane == 0) __builtin_nontemporal_store(out0, &op[0]);
    }
}

extern "C" void kernel_launch(void* const* d_in, const int* in_sizes, int n_in,
                              void* d_out, int out_size, void* d_ws, size_t ws_size,
                              hipStream_t stream) {
    const float* x   = (const float*)d_in[0];
    const float* anc = (const float*)d_in[1];
    float* out       = (float*)d_out;
    hipLaunchKernelGGL(hfield_kernel, dim3(1024), dim3(256), 0, stream, x, anc, out);
}